// Round 4
// baseline (270.362 us; speedup 1.0000x reference)
//
#include <hip/hip_runtime.h>
#include <hip/hip_bf16.h>

#define Bc 16
#define Nc 512
#define Dc 768
#define Hc 12
#define Ec 8
#define HDc 64
#define D3 (3 * Dc)   // 2304

typedef __hip_bfloat16 bf16;
typedef short bf16x8 __attribute__((ext_vector_type(8)));     // 8 bf16, 4 VGPR
typedef float f32x4 __attribute__((ext_vector_type(4)));
typedef unsigned short u16x4 __attribute__((ext_vector_type(4)));

__device__ __forceinline__ unsigned int f2bf(float f) {
    union { __hip_bfloat16 h; unsigned short u; } cv;
    cv.h = __float2bfloat16(f);
    return (unsigned int)cv.u;
}

__device__ __forceinline__ void gload16(const void* src, void* ldsDst) {
    __builtin_amdgcn_global_load_lds((const __attribute__((address_space(1))) void*)src,
                                     (__attribute__((address_space(3))) void*)ldsDst,
                                     16, 0, 0);
}

// ---------------- cast f32 -> bf16, 8 elems/thread ----------------
__global__ __launch_bounds__(256) void cast_bf16_kernel(const float* __restrict__ in,
                                                        bf16* __restrict__ out, int n8) {
    int i = blockIdx.x * 256 + threadIdx.x;
    if (i >= n8) return;
    f32x4 a = ((const f32x4*)in)[i * 2];
    f32x4 b = ((const f32x4*)in)[i * 2 + 1];
    unsigned short t[8];
#pragma unroll
    for (int j = 0; j < 4; ++j) { t[j] = (unsigned short)f2bf(a[j]); t[4 + j] = (unsigned short)f2bf(b[j]); }
    ((bf16x8*)out)[i] = *(bf16x8*)t;
}

// ---------------- gating fold: Wc[b][t*768+o][i] = sum_e g[b,e] W[e][o][i] (bf16 out) ----------------
__global__ __launch_bounds__(256) void combine_w_kernel(const float* __restrict__ g,
                                                        const float* __restrict__ W0,
                                                        const float* __restrict__ W1,
                                                        const float* __restrict__ W2,
                                                        bf16* __restrict__ Wc) {
    __shared__ float gs[Bc * Ec];
    int tid = threadIdx.x;
    if (tid < Bc * Ec) gs[tid] = g[tid];
    __syncthreads();
    int t = blockIdx.y;
    const float* W = (t == 0) ? W0 : ((t == 1) ? W1 : W2);
    const int P = Dc * Dc / 4;   // float4 positions
    int p = blockIdx.x * 256 + tid;
    if (p >= P) return;
    f32x4 w[Ec];
#pragma unroll
    for (int e = 0; e < Ec; ++e) w[e] = ((const f32x4*)W)[(size_t)e * P + p];
    int o = p / (Dc / 4), i4 = p - o * (Dc / 4);
#pragma unroll
    for (int b = 0; b < Bc; ++b) {
        f32x4 acc = {0.f, 0.f, 0.f, 0.f};
#pragma unroll
        for (int e = 0; e < Ec; ++e) {
            float ge = gs[b * Ec + e];
            acc[0] += ge * w[e][0]; acc[1] += ge * w[e][1];
            acc[2] += ge * w[e][2]; acc[3] += ge * w[e][3];
        }
        u16x4 ov;
#pragma unroll
        for (int j = 0; j < 4; ++j) ov[j] = (unsigned short)f2bf(acc[j]);
        *(u16x4*)&Wc[((size_t)b * D3 + t * Dc + o) * Dc + i4 * 4] = ov;
    }
}

__global__ __launch_bounds__(256) void combine_b_kernel(const float* __restrict__ g,
                                                        const float* __restrict__ b0,
                                                        const float* __restrict__ b1,
                                                        const float* __restrict__ b2,
                                                        float* __restrict__ bc) {
    int t = blockIdx.y;
    const float* bvec = (t == 0) ? b0 : ((t == 1) ? b1 : b2);
    int i = blockIdx.x * 256 + threadIdx.x;
    if (i >= Bc * Dc) return;
    int b = i / Dc, o = i - b * Dc;
    float acc = 0.f;
#pragma unroll
    for (int e = 0; e < Ec; ++e) acc += g[b * Ec + e] * bvec[e * Dc + o];
    bc[(size_t)b * D3 + t * Dc + o] = acc;
}

// ---------------- bf16 MFMA NT GEMM: C[z] = A[z] * B[z]^T (+ bias) ----------------
// 256 threads = 4 waves (2x2), tile BM x BN, BK=32, 16x16x32 MFMA.
template<int BM, int BN, bool OUT_BF16, bool BIAS>
__global__ __launch_bounds__(256) void gemm_mfma(const bf16* __restrict__ Ain,
                                                 const bf16* __restrict__ Bin,
                                                 void* __restrict__ Cout,
                                                 const float* __restrict__ bias,
                                                 int lda, int ldb, int ldc, int K,
                                                 long sA, long sB, long sC, int sBias) {
    constexpr int A_LDS = BM * 64;
    constexpr int B_LDS = BN * 64;
    __shared__ __align__(16) char lds[A_LDS + B_LDS];
    char* ldsA = lds;
    char* ldsB = lds + A_LDS;

    const int tid = threadIdx.x;
    const int lane = tid & 63;
    const int wave = tid >> 6;
    const int wr = wave >> 1, wc = wave & 1;
    constexpr int TM = BM / 32;
    constexpr int TN = BN / 32;
    const int m0 = blockIdx.y * BM;
    const int n0 = blockIdx.x * BN;
    const int z = blockIdx.z;
    const int mbase = wr * (BM / 2);
    const int nbase = wc * (BN / 2);

    const bf16* Ab = Ain + (size_t)z * sA;
    const bf16* Bb = Bin + (size_t)z * sB;

    f32x4 acc[TM][TN];
#pragma unroll
    for (int m = 0; m < TM; ++m)
#pragma unroll
        for (int n = 0; n < TN; ++n) acc[m][n] = f32x4{0.f, 0.f, 0.f, 0.f};

    constexpr int ACH = BM / 64;   // 1024B LDS chunks per wave
    constexpr int BCH = BN / 64;

    for (int k0 = 0; k0 < K; k0 += 32) {
        // ---- stage A tile ----
#pragma unroll
        for (int c = 0; c < ACH; ++c) {
            int q = wave * ACH + c;
            int row = q * 16 + (lane >> 2);
            int sl = (lane & 3) ^ (row & 3);
            const bf16* src = Ab + (size_t)(m0 + row) * lda + k0 + sl * 8;
            gload16(src, ldsA + q * 1024);
        }
        // ---- stage B tile ----
#pragma unroll
        for (int c = 0; c < BCH; ++c) {
            int q = wave * BCH + c;
            int row = q * 16 + (lane >> 2);
            int sl = (lane & 3) ^ (row & 3);
            const bf16* src = Bb + (size_t)(n0 + row) * ldb + k0 + sl * 8;
            gload16(src, ldsB + q * 1024);
        }
        __syncthreads();

        bf16x8 af[TM], bfr[TN];
#pragma unroll
        for (int m = 0; m < TM; ++m) {
            int r = mbase + m * 16 + (lane & 15);
            int sp = (lane >> 4) ^ (lane & 3);       // == (lane>>4) ^ (r&3)
            af[m] = *(const bf16x8*)(ldsA + r * 64 + sp * 16);
        }
#pragma unroll
        for (int n = 0; n < TN; ++n) {
            int r = nbase + n * 16 + (lane & 15);
            int sp = (lane >> 4) ^ (lane & 3);
            bfr[n] = *(const bf16x8*)(ldsB + r * 64 + sp * 16);
        }
#pragma unroll
        for (int m = 0; m < TM; ++m)
#pragma unroll
            for (int n = 0; n < TN; ++n)
                acc[m][n] = __builtin_amdgcn_mfma_f32_16x16x32_bf16(af[m], bfr[n], acc[m][n], 0, 0, 0);
        __syncthreads();
    }

    // ---- epilogue ----
    size_t cOff = (size_t)z * sC;
#pragma unroll
    for (int n = 0; n < TN; ++n) {
        int col = n0 + nbase + n * 16 + (lane & 15);
        float bv = 0.f;
        if constexpr (BIAS) bv = bias[(size_t)z * sBias + col];
#pragma unroll
        for (int m = 0; m < TM; ++m) {
            int row = m0 + mbase + m * 16 + (lane >> 4) * 4;
#pragma unroll
            for (int r = 0; r < 4; ++r) {
                float val = acc[m][n][r] + bv;
                if constexpr (OUT_BF16)
                    ((bf16*)Cout)[cOff + (size_t)(row + r) * ldc + col] = __float2bfloat16(val);
                else
                    ((float*)Cout)[cOff + (size_t)(row + r) * ldc + col] = val;
            }
        }
    }
}

// ---------------- Vt[z][d][k] = V[b][k][1536 + h*64 + d] (bf16) ----------------
__global__ __launch_bounds__(256) void transpose_v_kernel(const bf16* __restrict__ QKV,
                                                          bf16* __restrict__ Vt) {
    int z = blockIdx.y;
    int b = z / Hc, h = z - b * Hc;
    int k0 = blockIdx.x * 64;
    __shared__ bf16 t[64][72];
    const bf16* src = QKV + ((size_t)b * Nc + k0) * D3 + 2 * Dc + h * HDc;
#pragma unroll
    for (int it = 0; it < 2; ++it) {
        int idx = it * 256 + threadIdx.x;   // 0..511
        int r = idx >> 3, cg = idx & 7;
        bf16x8 v = *(const bf16x8*)(src + (size_t)r * D3 + cg * 8);
#pragma unroll
        for (int j = 0; j < 8; ++j) t[r][cg * 8 + j] = ((const bf16*)&v)[j];
    }
    __syncthreads();
    bf16* dst = Vt + (size_t)z * HDc * Nc + k0;
#pragma unroll
    for (int it = 0; it < 2; ++it) {
        int idx = it * 256 + threadIdx.x;
        int d = idx >> 3, kg = idx & 7;
        bf16 tmp[8];
#pragma unroll
        for (int j = 0; j < 8; ++j) tmp[j] = t[kg * 8 + j][d];
        *(bf16x8*)(dst + (size_t)d * Nc + kg * 8) = *(bf16x8*)tmp;
    }
}

// ---------------- fused: attn[z] = softmax(Q K^T / 8); ctx = attn @ V ----------------
// Swapped QK^T: mfma(K_frag, Q_frag) -> each lane owns one q-row (col = lane&15).
// Block = 128 threads (2 independent waves, 16 q-rows each, own 16KB LDS half). No barrier.
__global__ __launch_bounds__(128) void fused_attn_kernel(const bf16* __restrict__ QKV,
                                                         const bf16* __restrict__ Vt,
                                                         float* __restrict__ attn,
                                                         bf16* __restrict__ ctx) {
    __shared__ __align__(16) char plds[2][16384];   // per-wave P tile [16][512] bf16, XOR-swizzled
    int z = blockIdx.y;
    int b = z / Hc, h = z - b * Hc;
    int wave = threadIdx.x >> 6, lane = threadIdx.x & 63;
    int cl = lane & 15, hi = lane >> 4;
    int qbase = blockIdx.x * 32 + wave * 16;
    const bf16* Qb = QKV + (size_t)b * Nc * D3 + h * HDc;
    const bf16* Kb = Qb + Dc;
    int kq = hi * 8;

    bf16x8 qf0 = *(const bf16x8*)(Qb + (size_t)(qbase + cl) * D3 + kq);
    bf16x8 qf1 = *(const bf16x8*)(Qb + (size_t)(qbase + cl) * D3 + 32 + kq);

    // S^T tile: acc[n][r] = S[q = qbase+cl][k = 16n + 4hi + r]
    f32x4 acc[32];
#pragma unroll
    for (int n = 0; n < 32; ++n) {
        int krow = n * 16 + cl;
        bf16x8 k0 = *(const bf16x8*)(Kb + (size_t)krow * D3 + kq);
        bf16x8 k1 = *(const bf16x8*)(Kb + (size_t)krow * D3 + 32 + kq);
        f32x4 a = {0.f, 0.f, 0.f, 0.f};
        a = __builtin_amdgcn_mfma_f32_16x16x32_bf16(k0, qf0, a, 0, 0, 0);
        a = __builtin_amdgcn_mfma_f32_16x16x32_bf16(k1, qf1, a, 0, 0, 0);
        acc[n] = a;
    }

    // row softmax: lane owns whole row -> 128 local values + 2 shuffles
    const float sc = 0.125f;
    float mx = -1e30f;
#pragma unroll
    for (int n = 0; n < 32; ++n)
#pragma unroll
        for (int r = 0; r < 4; ++r) {
            acc[n][r] *= sc;
            mx = fmaxf(mx, acc[n][r]);
        }
    mx = fmaxf(mx, __shfl_xor(mx, 16));
    mx = fmaxf(mx, __shfl_xor(mx, 32));
    float sum = 0.f;
#pragma unroll
    for (int n = 0; n < 32; ++n)
#pragma unroll
        for (int r = 0; r < 4; ++r) {
            float e = __expf(acc[n][r] - mx);
            acc[n][r] = e;
            sum += e;
        }
    sum += __shfl_xor(sum, 16);
    sum += __shfl_xor(sum, 32);
    float inv = 1.0f / sum;

    // write attn (f32x4, k-contiguous) + P tile to own LDS (packed bf16 pairs, b64)
    float* arow = attn + (size_t)z * Nc * Nc + (size_t)(qbase + cl) * Nc;
    char* prow = plds[wave] + cl * 1024;
    int swz = (cl & 7) << 4;
#pragma unroll
    for (int n = 0; n < 32; ++n) {
        f32x4 p;
#pragma unroll
        for (int r = 0; r < 4; ++r) p[r] = acc[n][r] * inv;
        *(f32x4*)(arow + n * 16 + hi * 4) = p;
        uint2 w;
        w.x = f2bf(p[0]) | (f2bf(p[1]) << 16);
        w.y = f2bf(p[2]) | (f2bf(p[3]) << 16);
        *(uint2*)(prow + ((32 * n + 8 * hi) ^ swz)) = w;
    }

    // PV: A-frag = own P row (row = cl), B-frag = Vt rows from L2
    const bf16* Vtb = Vt + (size_t)z * HDc * Nc;
    f32x4 o4[4];
#pragma unroll
    for (int d0 = 0; d0 < 4; ++d0) o4[d0] = f32x4{0.f, 0.f, 0.f, 0.f};
#pragma unroll
    for (int ks = 0; ks < 16; ++ks) {
        bf16x8 pa = *(const bf16x8*)(prow + ((ks * 64 + hi * 16) ^ swz));
#pragma unroll
        for (int d0 = 0; d0 < 4; ++d0) {
            bf16x8 vb = *(const bf16x8*)(Vtb + (size_t)(d0 * 16 + cl) * Nc + ks * 32 + kq);
            o4[d0] = __builtin_amdgcn_mfma_f32_16x16x32_bf16(pa, vb, o4[d0], 0, 0, 0);
        }
    }
    bf16* cb = ctx + ((size_t)b * Nc + qbase + hi * 4) * Dc + h * HDc;
#pragma unroll
    for (int d0 = 0; d0 < 4; ++d0)
#pragma unroll
        for (int r = 0; r < 4; ++r)
            cb[(size_t)r * Dc + d0 * 16 + cl] = __float2bfloat16(o4[d0][r]);
}

extern "C" void kernel_launch(void* const* d_in, const int* in_sizes, int n_in,
                              void* d_out, int out_size, void* d_ws, size_t ws_size,
                              hipStream_t stream) {
    (void)in_sizes; (void)n_in; (void)out_size; (void)ws_size;
    const float* x  = (const float*)d_in[0];
    const float* g  = (const float*)d_in[1];
    const float* Wq = (const float*)d_in[2];
    const float* bq = (const float*)d_in[3];
    const float* Wk = (const float*)d_in[4];
    const float* bk = (const float*)d_in[5];
    const float* Wv = (const float*)d_in[6];
    const float* bv = (const float*)d_in[7];
    const float* Wo = (const float*)d_in[8];
    const float* bo = (const float*)d_in[9];

    float* out  = (float*)d_out;
    float* attn = out + (size_t)Bc * Nc * Dc;

    // workspace layout: x_bf | Wo_bf | bc | QKV | R{Wc -> Vt,ctx}
    char* w = (char*)d_ws;
    bf16* x_bf  = (bf16*)w;                              // 16*512*768
    bf16* Wo_bf = x_bf + (size_t)Bc * Nc * Dc;           // 768*768
    float* bc   = (float*)(Wo_bf + (size_t)Dc * Dc);     // 16*2304
    bf16* QKV   = (bf16*)(bc + (size_t)Bc * D3);         // 16*512*2304
    bf16* R     = QKV + (size_t)Bc * Nc * D3;            // reuse region
    bf16* Wc    = R;                                     // 16*2304*768 (phase 1)
    bf16* Vt    = R;                                     // 192*64*512  (phase 2)
    bf16* ctx   = R + (size_t)Bc * Hc * HDc * Nc;        // 16*512*768  (phase 2)

    dim3 blk(256);

    cast_bf16_kernel<<<(Bc * Nc * Dc / 8 + 255) / 256, blk, 0, stream>>>(x, x_bf, Bc * Nc * Dc / 8);
    cast_bf16_kernel<<<(Dc * Dc / 8 + 255) / 256, blk, 0, stream>>>(Wo, Wo_bf, Dc * Dc / 8);

    combine_w_kernel<<<dim3((Dc * Dc / 4 + 255) / 256, 3), blk, 0, stream>>>(g, Wq, Wk, Wv, Wc);
    combine_b_kernel<<<dim3((Bc * Dc + 255) / 256, 3), blk, 0, stream>>>(g, bq, bk, bv, bc);

    // QKV = x_bf @ Wc^T + bc   (bf16 out), M=512 N=2304 K=768, z=batch
    gemm_mfma<128, 128, true, true><<<dim3(D3 / 128, Nc / 128, Bc), blk, 0, stream>>>(
        x_bf, Wc, QKV, bc, Dc, Dc, D3, Dc,
        (long)Nc * Dc, (long)D3 * Dc, (long)Nc * D3, D3);

    // Vt[z] = V[b,:,h-block]^T
    transpose_v_kernel<<<dim3(Nc / 64, Bc * Hc), blk, 0, stream>>>(QKV, Vt);

    // attn (to d_out) + ctx = attn @ V  fused
    fused_attn_kernel<<<dim3(Nc / 32, Bc * Hc), dim3(128), 0, stream>>>(QKV, Vt, attn, ctx);

    // out = ctx @ Wo^T + bo   (f32 out), M=512 N=768 K=768
    gemm_mfma<128, 128, false, true><<<dim3(Dc / 128, Nc / 128, Bc), blk, 0, stream>>>(
        ctx, Wo_bf, out, bo, Dc, Dc, Dc, Dc,
        (long)Nc * Dc, 0L, (long)Nc * Dc, 0);
}

// Round 5
// 261.218 us; speedup vs baseline: 1.0350x; 1.0350x over previous
//
#include <hip/hip_runtime.h>
#include <hip/hip_bf16.h>

#define Bc 16
#define Nc 512
#define Dc 768
#define Hc 12
#define Ec 8
#define HDc 64
#define D3 (3 * Dc)   // 2304

typedef __hip_bfloat16 bf16;
typedef short bf16x8 __attribute__((ext_vector_type(8)));     // 8 bf16, 4 VGPR
typedef float f32x4 __attribute__((ext_vector_type(4)));
typedef unsigned short u16x4 __attribute__((ext_vector_type(4)));

__device__ __forceinline__ unsigned int f2bf(float f) {
    union { __hip_bfloat16 h; unsigned short u; } cv;
    cv.h = __float2bfloat16(f);
    return (unsigned int)cv.u;
}

__device__ __forceinline__ void gload16(const void* src, void* ldsDst) {
    __builtin_amdgcn_global_load_lds((const __attribute__((address_space(1))) void*)src,
                                     (__attribute__((address_space(3))) void*)ldsDst,
                                     16, 0, 0);
}

// ---------------- cast f32 -> bf16, 8 elems/thread ----------------
__global__ __launch_bounds__(256) void cast_bf16_kernel(const float* __restrict__ in,
                                                        bf16* __restrict__ out, int n8) {
    int i = blockIdx.x * 256 + threadIdx.x;
    if (i >= n8) return;
    f32x4 a = ((const f32x4*)in)[i * 2];
    f32x4 b = ((const f32x4*)in)[i * 2 + 1];
    unsigned short t[8];
#pragma unroll
    for (int j = 0; j < 4; ++j) { t[j] = (unsigned short)f2bf(a[j]); t[4 + j] = (unsigned short)f2bf(b[j]); }
    ((bf16x8*)out)[i] = *(bf16x8*)t;
}

// ---------------- gating fold: Wc[b][t*768+o][i] = sum_e g[b,e] W[e][o][i] (bf16 out) ----------------
__global__ __launch_bounds__(256) void combine_w_kernel(const float* __restrict__ g,
                                                        const float* __restrict__ W0,
                                                        const float* __restrict__ W1,
                                                        const float* __restrict__ W2,
                                                        bf16* __restrict__ Wc) {
    __shared__ float gs[Bc * Ec];
    int tid = threadIdx.x;
    if (tid < Bc * Ec) gs[tid] = g[tid];
    __syncthreads();
    int t = blockIdx.y;
    const float* W = (t == 0) ? W0 : ((t == 1) ? W1 : W2);
    const int P = Dc * Dc / 4;   // float4 positions
    int p = blockIdx.x * 256 + tid;
    if (p >= P) return;
    f32x4 w[Ec];
#pragma unroll
    for (int e = 0; e < Ec; ++e) w[e] = ((const f32x4*)W)[(size_t)e * P + p];
    int o = p / (Dc / 4), i4 = p - o * (Dc / 4);
#pragma unroll
    for (int b = 0; b < Bc; ++b) {
        f32x4 acc = {0.f, 0.f, 0.f, 0.f};
#pragma unroll
        for (int e = 0; e < Ec; ++e) {
            float ge = gs[b * Ec + e];
            acc[0] += ge * w[e][0]; acc[1] += ge * w[e][1];
            acc[2] += ge * w[e][2]; acc[3] += ge * w[e][3];
        }
        u16x4 ov;
#pragma unroll
        for (int j = 0; j < 4; ++j) ov[j] = (unsigned short)f2bf(acc[j]);
        *(u16x4*)&Wc[((size_t)b * D3 + t * Dc + o) * Dc + i4 * 4] = ov;
    }
}

__global__ __launch_bounds__(256) void combine_b_kernel(const float* __restrict__ g,
                                                        const float* __restrict__ b0,
                                                        const float* __restrict__ b1,
                                                        const float* __restrict__ b2,
                                                        float* __restrict__ bc) {
    int t = blockIdx.y;
    const float* bvec = (t == 0) ? b0 : ((t == 1) ? b1 : b2);
    int i = blockIdx.x * 256 + threadIdx.x;
    if (i >= Bc * Dc) return;
    int b = i / Dc, o = i - b * Dc;
    float acc = 0.f;
#pragma unroll
    for (int e = 0; e < Ec; ++e) acc += g[b * Ec + e] * bvec[e * Dc + o];
    bc[(size_t)b * D3 + t * Dc + o] = acc;
}

// ---------------- bf16 MFMA NT GEMM: C[z] = A[z] * B[z]^T (+ bias) ----------------
// 256 threads = 4 waves (2x2), tile BM x BN, BK=32, 16x16x32 MFMA.
template<int BM, int BN, bool OUT_BF16, bool BIAS>
__global__ __launch_bounds__(256) void gemm_mfma(const bf16* __restrict__ Ain,
                                                 const bf16* __restrict__ Bin,
                                                 void* __restrict__ Cout,
                                                 const float* __restrict__ bias,
                                                 int lda, int ldb, int ldc, int K,
                                                 long sA, long sB, long sC, int sBias) {
    constexpr int A_LDS = BM * 64;
    constexpr int B_LDS = BN * 64;
    __shared__ __align__(16) char lds[A_LDS + B_LDS];
    char* ldsA = lds;
    char* ldsB = lds + A_LDS;

    const int tid = threadIdx.x;
    const int lane = tid & 63;
    const int wave = tid >> 6;
    const int wr = wave >> 1, wc = wave & 1;
    constexpr int TM = BM / 32;
    constexpr int TN = BN / 32;
    const int m0 = blockIdx.y * BM;
    const int n0 = blockIdx.x * BN;
    const int z = blockIdx.z;
    const int mbase = wr * (BM / 2);
    const int nbase = wc * (BN / 2);

    const bf16* Ab = Ain + (size_t)z * sA;
    const bf16* Bb = Bin + (size_t)z * sB;

    f32x4 acc[TM][TN];
#pragma unroll
    for (int m = 0; m < TM; ++m)
#pragma unroll
        for (int n = 0; n < TN; ++n) acc[m][n] = f32x4{0.f, 0.f, 0.f, 0.f};

    constexpr int ACH = BM / 64;   // 1024B LDS chunks per wave
    constexpr int BCH = BN / 64;

    for (int k0 = 0; k0 < K; k0 += 32) {
        // ---- stage A tile ----
#pragma unroll
        for (int c = 0; c < ACH; ++c) {
            int q = wave * ACH + c;
            int row = q * 16 + (lane >> 2);
            int sl = (lane & 3) ^ (row & 3);
            const bf16* src = Ab + (size_t)(m0 + row) * lda + k0 + sl * 8;
            gload16(src, ldsA + q * 1024);
        }
        // ---- stage B tile ----
#pragma unroll
        for (int c = 0; c < BCH; ++c) {
            int q = wave * BCH + c;
            int row = q * 16 + (lane >> 2);
            int sl = (lane & 3) ^ (row & 3);
            const bf16* src = Bb + (size_t)(n0 + row) * ldb + k0 + sl * 8;
            gload16(src, ldsB + q * 1024);
        }
        __syncthreads();

        bf16x8 af[TM], bfr[TN];
#pragma unroll
        for (int m = 0; m < TM; ++m) {
            int r = mbase + m * 16 + (lane & 15);
            int sp = (lane >> 4) ^ (lane & 3);       // == (lane>>4) ^ (r&3)
            af[m] = *(const bf16x8*)(ldsA + r * 64 + sp * 16);
        }
#pragma unroll
        for (int n = 0; n < TN; ++n) {
            int r = nbase + n * 16 + (lane & 15);
            int sp = (lane >> 4) ^ (lane & 3);
            bfr[n] = *(const bf16x8*)(ldsB + r * 64 + sp * 16);
        }
#pragma unroll
        for (int m = 0; m < TM; ++m)
#pragma unroll
            for (int n = 0; n < TN; ++n)
                acc[m][n] = __builtin_amdgcn_mfma_f32_16x16x32_bf16(af[m], bfr[n], acc[m][n], 0, 0, 0);
        __syncthreads();
    }

    // ---- epilogue ----
    size_t cOff = (size_t)z * sC;
#pragma unroll
    for (int n = 0; n < TN; ++n) {
        int col = n0 + nbase + n * 16 + (lane & 15);
        float bv = 0.f;
        if constexpr (BIAS) bv = bias[(size_t)z * sBias + col];
#pragma unroll
        for (int m = 0; m < TM; ++m) {
            int row = m0 + mbase + m * 16 + (lane >> 4) * 4;
#pragma unroll
            for (int r = 0; r < 4; ++r) {
                float val = acc[m][n][r] + bv;
                if constexpr (OUT_BF16)
                    ((bf16*)Cout)[cOff + (size_t)(row + r) * ldc + col] = __float2bfloat16(val);
                else
                    ((float*)Cout)[cOff + (size_t)(row + r) * ldc + col] = val;
            }
        }
    }
}

// ---------------- repack K and V for the fused attention kernel ----------------
// Kz[z][r][d]          = QKV[b][r][768 + h*64 + d]              (compact, contiguous per z)
// Vp[z][c][d0][l][j]   = QKV[b][ c*32 + ((j>>2)&1)*16 + (l>>4)*4 + (j&3) ][1536 + h*64 + d0*16 + (l&15)]
// (Vp is the PV A-fragment with the permuted-k contraction order; see fused_attn_kernel.)
__global__ __launch_bounds__(256) void repack_kv_kernel(const bf16* __restrict__ QKV,
                                                        bf16* __restrict__ Kz,
                                                        bf16* __restrict__ Vp) {
    __shared__ bf16 vlds[128][72];
    int z = blockIdx.y;
    int b = z / Hc, h = z - b * Hc;
    int k0 = blockIdx.x * 128;
    int tid = threadIdx.x;
    const bf16* Ks = QKV + (size_t)b * Nc * D3 + Dc + h * HDc;
    const bf16* Vs = Ks + Dc;

    // K: copy 128x64 tile to compact layout; V: stage same-shape tile to LDS
#pragma unroll
    for (int it = 0; it < 4; ++it) {
        int idx = it * 256 + tid;              // 0..1023
        int r = idx >> 3, c8 = idx & 7;
        bf16x8 kv = *(const bf16x8*)(Ks + (size_t)(k0 + r) * D3 + c8 * 8);
        *(bf16x8*)(&Kz[((size_t)z * Nc + k0 + r) * HDc + c8 * 8]) = kv;
        bf16x8 vv = *(const bf16x8*)(Vs + (size_t)(k0 + r) * D3 + c8 * 8);
        *(bf16x8*)(&vlds[r][c8 * 8]) = vv;
    }
    __syncthreads();

    // V fragments
#pragma unroll
    for (int it = 0; it < 4; ++it) {
        int idx = it * 256 + tid;              // 0..1023 = (c_local, d0, l)
        int l = idx & 63, d0 = (idx >> 6) & 3, c_local = idx >> 8;
        int cl = l & 15, hi = l >> 4;
        unsigned short t[8];
#pragma unroll
        for (int j = 0; j < 8; ++j) {
            int row = c_local * 32 + ((j >> 2) & 1) * 16 + hi * 4 + (j & 3);
            union { bf16 h; unsigned short u; } cv;
            cv.h = vlds[row][d0 * 16 + cl];
            t[j] = cv.u;
        }
        int c = blockIdx.x * 4 + c_local;
        *(bf16x8*)(&Vp[(((size_t)z * 16 + c) * 4 + d0) * 512 + l * 8]) = *(bf16x8*)t;
    }
}

// ---------------- fused: attn[z] = softmax(Q K^T / 8) -> d_out; ctx = attn @ V ----------------
// Swapped QK^T: mfma(K,Q) -> lane owns one full q-row: acc[n][r] = S[q=cl][k=16n+4hi+r].
// PV uses a permuted-k contraction (local l=8hi+j <-> global k=32c+16*(j>=4)+4hi+(j&3)),
// matching Vp's fragment layout -> P never leaves registers. No LDS, no barriers.
__global__ __launch_bounds__(256) void fused_attn_kernel(const bf16* __restrict__ QKV,
                                                         const bf16* __restrict__ Kz,
                                                         const bf16* __restrict__ Vp,
                                                         float* __restrict__ attn,
                                                         bf16* __restrict__ ctx) {
    int z = blockIdx.y;
    int b = z / Hc, h = z - b * Hc;
    int wave = threadIdx.x >> 6, lane = threadIdx.x & 63;
    int cl = lane & 15, hi = lane >> 4;
    int qbase = blockIdx.x * 64 + wave * 16;

    const bf16* Qb = QKV + (size_t)b * Nc * D3 + h * HDc;
    bf16x8 qf0 = *(const bf16x8*)(Qb + (size_t)(qbase + cl) * D3 + hi * 8);
    bf16x8 qf1 = *(const bf16x8*)(Qb + (size_t)(qbase + cl) * D3 + 32 + hi * 8);

    const bf16* Kb = Kz + (size_t)z * Nc * HDc;
    f32x4 acc[32];
#pragma unroll
    for (int n = 0; n < 32; ++n) {
        const bf16* krow = Kb + (n * 16 + cl) * HDc + hi * 8;
        bf16x8 k0 = *(const bf16x8*)(krow);
        bf16x8 k1 = *(const bf16x8*)(krow + 32);
        f32x4 a = {0.f, 0.f, 0.f, 0.f};
        a = __builtin_amdgcn_mfma_f32_16x16x32_bf16(k0, qf0, a, 0, 0, 0);
        a = __builtin_amdgcn_mfma_f32_16x16x32_bf16(k1, qf1, a, 0, 0, 0);
        acc[n] = a;
    }

    // row softmax, 4 parallel chains then 2 shuffles
    const float sc = 0.125f;
    f32x4 mx4 = acc[0];
#pragma unroll
    for (int n = 1; n < 32; ++n)
#pragma unroll
        for (int r = 0; r < 4; ++r) mx4[r] = fmaxf(mx4[r], acc[n][r]);
    float mx = fmaxf(fmaxf(mx4[0], mx4[1]), fmaxf(mx4[2], mx4[3])) * sc;
    mx = fmaxf(mx, __shfl_xor(mx, 16));
    mx = fmaxf(mx, __shfl_xor(mx, 32));
    f32x4 sum4 = {0.f, 0.f, 0.f, 0.f};
#pragma unroll
    for (int n = 0; n < 32; ++n)
#pragma unroll
        for (int r = 0; r < 4; ++r) {
            float e = __expf(acc[n][r] * sc - mx);
            acc[n][r] = e;
            sum4[r] += e;
        }
    float sum = (sum4[0] + sum4[1]) + (sum4[2] + sum4[3]);
    sum += __shfl_xor(sum, 16);
    sum += __shfl_xor(sum, 32);
    float inv = 1.0f / sum;

    // store attn (f32, k-contiguous 16B per n) + pack P to bf16 in registers
    float* arow = attn + (size_t)z * Nc * Nc + (size_t)(qbase + cl) * Nc;
    unsigned int pb[64];
#pragma unroll
    for (int n = 0; n < 32; ++n) {
        f32x4 p;
#pragma unroll
        for (int r = 0; r < 4; ++r) p[r] = acc[n][r] * inv;
        *(f32x4*)(arow + n * 16 + hi * 4) = p;
        pb[2 * n]     = f2bf(p[0]) | (f2bf(p[1]) << 16);
        pb[2 * n + 1] = f2bf(p[2]) | (f2bf(p[3]) << 16);
    }

    // PV: B-frag = own P slices (permuted k), A-frag = Vp (coalesced lane*16B)
    const bf16* Vb = Vp + (size_t)z * 16 * 4 * 512;
    f32x4 o4[4];
#pragma unroll
    for (int d0 = 0; d0 < 4; ++d0) o4[d0] = f32x4{0.f, 0.f, 0.f, 0.f};
#pragma unroll
    for (int c = 0; c < 16; ++c) {
        union { unsigned int u[4]; bf16x8 v; } pf;
        pf.u[0] = pb[4 * c];     pf.u[1] = pb[4 * c + 1];
        pf.u[2] = pb[4 * c + 2]; pf.u[3] = pb[4 * c + 3];
#pragma unroll
        for (int d0 = 0; d0 < 4; ++d0) {
            bf16x8 vf = *(const bf16x8*)(Vb + ((c * 4 + d0) * 64 + lane) * 8);
            o4[d0] = __builtin_amdgcn_mfma_f32_16x16x32_bf16(vf, pf.v, o4[d0], 0, 0, 0);
        }
    }

    // ctx[q = qbase+cl][h*64 + d0*16 + hi*4 + r]  (4 packed bf16 = 8B per d0)
    bf16* cb = ctx + ((size_t)b * Nc + qbase + cl) * Dc + h * HDc;
#pragma unroll
    for (int d0 = 0; d0 < 4; ++d0) {
        unsigned int w0 = f2bf(o4[d0][0]) | (f2bf(o4[d0][1]) << 16);
        unsigned int w1 = f2bf(o4[d0][2]) | (f2bf(o4[d0][3]) << 16);
        uint2 wv = {w0, w1};
        *(uint2*)(cb + d0 * 16 + hi * 4) = wv;
    }
}

extern "C" void kernel_launch(void* const* d_in, const int* in_sizes, int n_in,
                              void* d_out, int out_size, void* d_ws, size_t ws_size,
                              hipStream_t stream) {
    (void)in_sizes; (void)n_in; (void)out_size; (void)ws_size;
    const float* x  = (const float*)d_in[0];
    const float* g  = (const float*)d_in[1];
    const float* Wq = (const float*)d_in[2];
    const float* bq = (const float*)d_in[3];
    const float* Wk = (const float*)d_in[4];
    const float* bk = (const float*)d_in[5];
    const float* Wv = (const float*)d_in[6];
    const float* bv = (const float*)d_in[7];
    const float* Wo = (const float*)d_in[8];
    const float* bo = (const float*)d_in[9];

    float* out  = (float*)d_out;
    float* attn = out + (size_t)Bc * Nc * Dc;

    // workspace: x_bf | Wo_bf | bc | QKV | R{Wc (phase1) -> Kz,Vp,ctx (phase2)}
    char* w = (char*)d_ws;
    bf16* x_bf  = (bf16*)w;                              // 16*512*768
    bf16* Wo_bf = x_bf + (size_t)Bc * Nc * Dc;           // 768*768
    float* bc   = (float*)(Wo_bf + (size_t)Dc * Dc);     // 16*2304
    bf16* QKV   = (bf16*)(bc + (size_t)Bc * D3);         // 16*512*2304
    bf16* R     = QKV + (size_t)Bc * Nc * D3;            // reuse region (16*2304*768)
    bf16* Wc    = R;                                     // phase 1
    bf16* Kz    = R;                                     // 192*512*64
    bf16* Vp    = Kz + (size_t)Bc * Hc * Nc * HDc;       // 192*512*64
    bf16* ctx   = Vp + (size_t)Bc * Hc * Nc * HDc;       // 16*512*768

    dim3 blk(256);

    cast_bf16_kernel<<<(Bc * Nc * Dc / 8 + 255) / 256, blk, 0, stream>>>(x, x_bf, Bc * Nc * Dc / 8);
    cast_bf16_kernel<<<(Dc * Dc / 8 + 255) / 256, blk, 0, stream>>>(Wo, Wo_bf, Dc * Dc / 8);

    combine_w_kernel<<<dim3((Dc * Dc / 4 + 255) / 256, 3), blk, 0, stream>>>(g, Wq, Wk, Wv, Wc);
    combine_b_kernel<<<dim3((Bc * Dc + 255) / 256, 3), blk, 0, stream>>>(g, bq, bk, bv, bc);

    // QKV = x_bf @ Wc^T + bc   (bf16 out), M=512 N=2304 K=768, z=batch
    gemm_mfma<128, 128, true, true><<<dim3(D3 / 128, Nc / 128, Bc), blk, 0, stream>>>(
        x_bf, Wc, QKV, bc, Dc, Dc, D3, Dc,
        (long)Nc * Dc, (long)D3 * Dc, (long)Nc * D3, D3);

    // repack K (compact) and V (PV fragments)
    repack_kv_kernel<<<dim3(Nc / 128, Bc * Hc), blk, 0, stream>>>(QKV, Kz, Vp);

    // attn (to d_out) + ctx, fused, LDS-free
    fused_attn_kernel<<<dim3(Nc / 64, Bc * Hc), blk, 0, stream>>>(QKV, Kz, Vp, attn, ctx);

    // out = ctx @ Wo^T + bo   (f32 out), M=512 N=768 K=768
    gemm_mfma<128, 128, false, true><<<dim3(Dc / 128, Nc / 128, Bc), blk, 0, stream>>>(
        ctx, Wo_bf, out, bo, Dc, Dc, Dc, Dc,
        (long)Nc * Dc, 0L, (long)Nc * Dc, 0);
}